// Round 11
// baseline (160.589 us; speedup 1.0000x reference)
//
#include <hip/hip_runtime.h>

#define C_     20
#define H_     64
#define W_     2048
#define HW_    (H_*W_)
#define TH     8
#define TW     64
#define TR     (TH+4)      // 12
#define TC     (TW+4)      // 68
#define PLANE  (TR*TC)     // 816
#define DELEMS (C_*PLANE)  // 16320
#define DPAD   16384       // 64*256
#define NTHR   256
#define DSTG   64

// async global->LDS: wave-uniform LDS base (+lane*4 in HW); per-lane global src
#define GLOAD_LDS(SRC, DST)                                                     \
    __builtin_amdgcn_global_load_lds(                                           \
        (const __attribute__((address_space(1))) void*)(SRC),                   \
        (__attribute__((address_space(3))) void*)(DST), 4, 0, 0)

__global__ __launch_bounds__(NTHR) void lp_kernel(
    const float* __restrict__ data,
    const float* __restrict__ mask,
    const float* __restrict__ bilat,
    const float* __restrict__ ang_w,
    const float* __restrict__ bi_w,
    const float* __restrict__ zbuf,
    float* __restrict__ out)
{
    __shared__ float s_data[DPAD];   // 64 KB: 20 class planes [cls][12][68]
    __shared__ float s_mask[1024];   // 4 KB -> 68.6 KB total = 2 blocks/CU (the cap)

    const int tid = threadIdx.x;
    int bid = blockIdx.x;
    bid = (bid & 7)*64 + (bid >> 3);     // XCD swizzle (512 % 8 == 0, bijective)

    const int tx = bid & 31;             // W/TW = 32
    const int ty = (bid >> 5) & 7;       // H/TH = 8
    const int b  = bid >> 8;
    const int y0 = ty*TH, x0 = tx*TW;

    const float* dbase = data + (size_t)b*C_*HW_;
    const float* mbase = mask + (size_t)b*HW_;
    const int wbase = tid & ~63;

    // ---- async DMA: all 20 class planes (no registers held) ----
#pragma unroll
    for (int s = 0; s < DSTG; ++s) {
        const int idx = tid + s*NTHR;
        const int cls = idx / PLANE;
        const int rem = idx - cls*PLANE;
        const int r   = rem / TC;
        const int col = rem - r*TC;
        const int gy = y0 + r - 2, gx = x0 + col - 2;
        const bool ok = (idx < DELEMS) & (gy >= 0) & (gy < H_) & (gx >= 0) & (gx < W_);
        const float* src = ok ? (dbase + (size_t)cls*HW_ + (gy*W_ + gx)) : zbuf;
        GLOAD_LDS(src, s_data + s*NTHR + wbase);
    }
    // ---- async DMA: mask tile ----
#pragma unroll
    for (int s = 0; s < 4; ++s) {
        const int idx = tid + s*NTHR;
        const int r   = idx / TC;
        const int col = idx - r*TC;
        const int gy = y0 + r - 2, gx = x0 + col - 2;
        const bool ok = (idx < PLANE) & (gy >= 0) & (gy < H_) & (gx >= 0) & (gx < W_);
        const float* src = ok ? (mbase + (gy*W_ + gx)) : zbuf;
        GLOAD_LDS(src, s_mask + s*NTHR + wbase);
    }

    // thread -> 2 adjacent pixels (x, x+1)
    const int lxp = tid & 31;            // x-pair index
    const int lyy = tid >> 5;            // tile row 0..7
    const int lx2 = lxp*2;
    const int y = y0 + lyy, x = x0 + lx2;

    // bilateral for both pixels (float2 -> dwordx2, issued before the barrier)
    float bb0[24], bb1[24];
    {
        const float* bibase = bilat + (size_t)b*24*HW_ + (size_t)y*W_ + x;
#pragma unroll
        for (int kp = 0; kp < 24; ++kp) {
            const float2 vv = *reinterpret_cast<const float2*>(bibase + (size_t)kp*HW_);
            bb0[kp] = vv.x; bb1[kp] = vv.y;
        }
    }

    __syncthreads();   // drains all DMA

    // mask row segments: 5 rows x 6 cols serve both pixels' taps (register-resident)
    float msk[5][6];
#pragma unroll
    for (int i = 0; i < 5; ++i)
#pragma unroll
        for (int u = 0; u < 6; ++u)
            msk[i][u] = s_mask[(lyy + i)*TC + lx2 + u];
    const float m_c0 = msk[2][2], m_c1 = msk[2][3];

    float bi0[C_], bi1[C_], bg0[C_], bg1[C_];
#pragma unroll
    for (int c = 0; c < C_; ++c) { bi0[c] = 0.0f; bi1[c] = 0.0f; }

    float* aout = out + ((size_t)b*C_*H_ + y)*W_ + x;
    float* bout = aout + (size_t)2*C_*HW_;

#pragma unroll
    for (int cls = 0; cls < C_; ++cls) {
        float a0 = 0.0f, a1 = 0.0f, ba0 = 0.0f, ba1 = 0.0f;
        const float* srow = s_data + cls*PLANE + lyy*TC + lx2;
#pragma unroll
        for (int i = 0; i < 5; ++i) {
            float v[6];
#pragma unroll
            for (int u = 0; u < 6; ++u) v[u] = srow[i*TC + u];   // merges to b64/b128
            float pm[6];
#pragma unroll
            for (int u = 0; u < 6; ++u) pm[u] = v[u]*msk[i][u];  // shared by both px
#pragma unroll
            for (int j = 0; j < 5; ++j) {
                const int kk = i*5 + j;
                if (kk == 12) continue;                 // center (both px centers)
                const int k = (kk > 12) ? kk - 1 : kk;  // tap index 0..23
                const float wa = ang_w[cls*25 + kk];    // wave-uniform -> s_load
                const float wb = bi_w [cls*25 + kk];
                a0  += wa*v[j];   a1  += wa*v[j+1];
                ba0 += wb*v[j];   ba1 += wb*v[j+1];
                const int flat = k*C_ + cls;            // torch .view remap
                const int c2 = flat / 24, u24 = flat % 24;
                bi0[c2] += bb0[u24]*pm[j];
                bi1[c2] += bb1[u24]*pm[j+1];
            }
        }
        const float2 av = {a0, a1};
        *reinterpret_cast<float2*>(aout + (size_t)cls*HW_) = av;
        bg0[cls] = ba0; bg1[cls] = ba1;
    }

#pragma unroll
    for (int c = 0; c < C_; ++c) {
        const float2 bv = {m_c0*bg0[c]*bi0[c], m_c1*bg1[c]*bi1[c]};
        *reinterpret_cast<float2*>(bout + (size_t)c*HW_) = bv;
    }
}

extern "C" void kernel_launch(void* const* d_in, const int* in_sizes, int n_in,
                              void* d_out, int out_size, void* d_ws, size_t ws_size,
                              hipStream_t stream) {
    const float* data  = (const float*)d_in[0];
    const float* mask  = (const float*)d_in[1];
    const float* bilat = (const float*)d_in[2];
    const float* ang_w = (const float*)d_in[3];
    const float* bi_w  = (const float*)d_in[4];
    float* out = (float*)d_out;

    hipMemsetAsync(d_ws, 0, 256, stream);   // zero word for OOB halo lanes

    const int nblocks = 2 * (H_/TH) * (W_/TW);  // 512 blocks x 256 thr (2 px/thread)
    lp_kernel<<<nblocks, NTHR, 0, stream>>>(data, mask, bilat, ang_w, bi_w,
                                            (const float*)d_ws, out);
}

// Round 12
// 61.813 us; speedup vs baseline: 2.5980x; 2.5980x over previous
//
#include <hip/hip_runtime.h>

#define C_     20
#define H_     64
#define W_     2048
#define HW_    (H_*W_)
#define TH     8
#define TW     64
#define TR     (TH+4)      // 12
#define TC     (TW+4)      // 68
#define PLANE  (TR*TC)     // 816
#define DELEMS (C_*PLANE)  // 16320
#define DPAD   16384       // 64*256
#define NTHR   256
#define DSTG   64

// async global->LDS: wave-uniform LDS base (+lane*4 in HW); per-lane global src
#define GLOAD_LDS(SRC, DST)                                                     \
    __builtin_amdgcn_global_load_lds(                                           \
        (const __attribute__((address_space(1))) void*)(SRC),                   \
        (__attribute__((address_space(3))) void*)(DST), 4, 0, 0)

// One residue group RG: classes {RG, RG+4, RG+8, RG+12, RG+16}.
// These classes' bilateral indices u24 = (20k+cls)%24 are all === RG (mod 4),
// so only 6 bb values per pixel are live (bbsub), not 24.  [proven round 8]
template<int RG>
__device__ __forceinline__ void compute_group(
    const float* __restrict__ s_data, int lyy, int lx2,
    const float* __restrict__ ang_w, const float* __restrict__ bi_w,
    const float* __restrict__ bibase,
    const float (&msk)[5][6],
    float (&bi0)[C_], float (&bi1)[C_],
    float (&bg0)[C_], float (&bg1)[C_],
    float* __restrict__ aout)
{
    // 6 bilateral planes for this residue (float2 covers both pixels)
    float bs0[6], bs1[6];
#pragma unroll
    for (int u = 0; u < 6; ++u) {
        const float2 vv = *reinterpret_cast<const float2*>(bibase + (size_t)(RG + 4*u)*HW_);
        bs0[u] = vv.x; bs1[u] = vv.y;
    }

#pragma unroll
    for (int t = 0; t < 5; ++t) {
        const int cls = RG + 4*t;
        float a0 = 0.0f, a1 = 0.0f, ba0 = 0.0f, ba1 = 0.0f;
        const float* srow = s_data + cls*PLANE + lyy*TC + lx2;
#pragma unroll
        for (int i = 0; i < 5; ++i) {
            float v[6];
#pragma unroll
            for (int u = 0; u < 6; ++u) v[u] = srow[i*TC + u];   // merges to b64/b128
            float pm[6];
#pragma unroll
            for (int u = 0; u < 6; ++u) pm[u] = v[u]*msk[i][u];  // shared by both px
#pragma unroll
            for (int j = 0; j < 5; ++j) {
                const int kk = i*5 + j;
                if (kk == 12) continue;                 // zeroed center tap
                const int k = (kk > 12) ? kk - 1 : kk;  // tap index 0..23
                const float wa = ang_w[cls*25 + kk];    // wave-uniform -> s_load
                const float wb = bi_w [cls*25 + kk];
                a0  += wa*v[j];   a1  += wa*v[j+1];
                ba0 += wb*v[j];   ba1 += wb*v[j+1];
                const int flat = k*C_ + cls;            // torch .view remap
                const int c2 = flat / 24;
                const int u  = ((flat % 24) - RG) / 4;  // bbsub slot
                bi0[c2] += bs0[u]*pm[j];
                bi1[c2] += bs1[u]*pm[j+1];
            }
        }
        const float2 av = {a0, a1};
        *reinterpret_cast<float2*>(aout + (size_t)cls*HW_) = av;
        bg0[cls] = ba0; bg1[cls] = ba1;
    }
}

__global__ __launch_bounds__(NTHR) void lp_kernel(
    const float* __restrict__ data,
    const float* __restrict__ mask,
    const float* __restrict__ bilat,
    const float* __restrict__ ang_w,
    const float* __restrict__ bi_w,
    const float* __restrict__ zbuf,
    float* __restrict__ out)
{
    __shared__ float s_data[DPAD];   // 64 KB: 20 class planes [cls][12][68]
    __shared__ float s_mask[1024];   // 4 KB

    const int tid = threadIdx.x;
    int bid = blockIdx.x;
    bid = (bid & 7)*64 + (bid >> 3);     // XCD swizzle (512 % 8 == 0, bijective)

    const int tx = bid & 31;             // W/TW = 32
    const int ty = (bid >> 5) & 7;       // H/TH = 8
    const int b  = bid >> 8;
    const int y0 = ty*TH, x0 = tx*TW;

    const float* dbase = data + (size_t)b*C_*HW_;
    const float* mbase = mask + (size_t)b*HW_;
    const int wbase = tid & ~63;

    // ---- async DMA: all 20 class planes (no registers held) ----
#pragma unroll
    for (int s = 0; s < DSTG; ++s) {
        const int idx = tid + s*NTHR;
        const int cls = idx / PLANE;
        const int rem = idx - cls*PLANE;
        const int r   = rem / TC;
        const int col = rem - r*TC;
        const int gy = y0 + r - 2, gx = x0 + col - 2;
        const bool ok = (idx < DELEMS) & (gy >= 0) & (gy < H_) & (gx >= 0) & (gx < W_);
        const float* src = ok ? (dbase + (size_t)cls*HW_ + (gy*W_ + gx)) : zbuf;
        GLOAD_LDS(src, s_data + s*NTHR + wbase);
    }
    // ---- async DMA: mask tile ----
#pragma unroll
    for (int s = 0; s < 4; ++s) {
        const int idx = tid + s*NTHR;
        const int r   = idx / TC;
        const int col = idx - r*TC;
        const int gy = y0 + r - 2, gx = x0 + col - 2;
        const bool ok = (idx < PLANE) & (gy >= 0) & (gy < H_) & (gx >= 0) & (gx < W_);
        const float* src = ok ? (mbase + (gy*W_ + gx)) : zbuf;
        GLOAD_LDS(src, s_mask + s*NTHR + wbase);
    }

    // thread -> 2 adjacent pixels (x, x+1)
    const int lxp = tid & 31;            // x-pair index
    const int lyy = tid >> 5;            // tile row 0..7
    const int lx2 = lxp*2;
    const int y = y0 + lyy, x = x0 + lx2;

    const float* bibase = bilat + (size_t)b*24*HW_ + (size_t)y*W_ + x;

    __syncthreads();   // drains all DMA

    // mask row segments serve both pixels' taps (register-resident, 30 regs)
    float msk[5][6];
#pragma unroll
    for (int i = 0; i < 5; ++i)
#pragma unroll
        for (int u = 0; u < 6; ++u)
            msk[i][u] = s_mask[(lyy + i)*TC + lx2 + u];
    const float m_c0 = msk[2][2], m_c1 = msk[2][3];

    float bi0[C_], bi1[C_], bg0[C_], bg1[C_];
#pragma unroll
    for (int c = 0; c < C_; ++c) { bi0[c] = 0.0f; bi1[c] = 0.0f; }

    float* aout = out + ((size_t)b*C_*H_ + y)*W_ + x;
    float* bout = aout + (size_t)2*C_*HW_;

    // 4 residue groups, scheduler-fenced to cap register pressure
    compute_group<0>(s_data, lyy, lx2, ang_w, bi_w, bibase, msk, bi0, bi1, bg0, bg1, aout);
    __builtin_amdgcn_sched_barrier(0);
    compute_group<1>(s_data, lyy, lx2, ang_w, bi_w, bibase, msk, bi0, bi1, bg0, bg1, aout);
    __builtin_amdgcn_sched_barrier(0);
    compute_group<2>(s_data, lyy, lx2, ang_w, bi_w, bibase, msk, bi0, bi1, bg0, bg1, aout);
    __builtin_amdgcn_sched_barrier(0);
    compute_group<3>(s_data, lyy, lx2, ang_w, bi_w, bibase, msk, bi0, bi1, bg0, bg1, aout);

#pragma unroll
    for (int c = 0; c < C_; ++c) {
        const float2 bv = {m_c0*bg0[c]*bi0[c], m_c1*bg1[c]*bi1[c]};
        *reinterpret_cast<float2*>(bout + (size_t)c*HW_) = bv;
    }
}

extern "C" void kernel_launch(void* const* d_in, const int* in_sizes, int n_in,
                              void* d_out, int out_size, void* d_ws, size_t ws_size,
                              hipStream_t stream) {
    const float* data  = (const float*)d_in[0];
    const float* mask  = (const float*)d_in[1];
    const float* bilat = (const float*)d_in[2];
    const float* ang_w = (const float*)d_in[3];
    const float* bi_w  = (const float*)d_in[4];
    float* out = (float*)d_out;

    hipMemsetAsync(d_ws, 0, 256, stream);   // zero word for OOB halo lanes

    const int nblocks = 2 * (H_/TH) * (W_/TW);  // 512 blocks x 256 thr (2 px/thread)
    lp_kernel<<<nblocks, NTHR, 0, stream>>>(data, mask, bilat, ang_w, bi_w,
                                            (const float*)d_ws, out);
}